// Round 6
// baseline (68.176 us; speedup 1.0000x reference)
//
#include <hip/hip_runtime.h>
#include <math.h>

// x: (1,3,48,48,48) fp32. out[v] = sum(g*wd*p)/sum(g*wd); normalizations cancel.
// s-transform: e = exp2(-(K*(p-c))^2 + Lc), K = sqrt(0.78125*log2(e)), so the
// exp argument is ONE fma: s = fma(p,K,-c*K); arg = fma(-s,s,Lc).
// Packed fp32: both outputs of the w-pair ride in one ext_vector<float,2> so
// the backend emits v_pk_fma_f32 / v_pk_add_f32 (full-rate on CDNA2+).
// Round 6 model: ~40.4us harness ws-poison fill + ~20us fixed graph overhead
// + ~5-9us kernel (issue-bound). This cuts the kernel's VALU slots ~1.7x.

typedef float v2f __attribute__((ext_vector_type(2)));

__global__ __launch_bounds__(64)
void bilateral3d(const float* __restrict__ x, float* __restrict__ out) {
    constexpr float K  = 1.0616523f;    // sqrt(0.78125 * log2(e))
    constexpr float L0 = -2.3846116f;   // -4/2.42 * log2(e)
    constexpr float L1 = -0.5961529f;   // L0/4
    const float LGc[5] = {L0, L1, 0.0f, L1, L0};

    const int P   = blockIdx.x * 64 + threadIdx.x;  // pair id, 0..165887
    const int pw  = P % 24;
    const int t   = P / 24;
    const int ph  = t % 48;
    const int pcd = t / 48;             // c*48 + d
    const int w0  = pw * 2;
    const int d0  = pcd % 48;
    const int dz  = pcd - d0;

    const bool left  = (pw == 0);
    const bool right = (pw == 23);
    const int a_off = left  ? 0 : (w0 - 2);  // 8B-aligned, in-bounds
    const int c_off = right ? 0 : (w0 + 2);  // dummy 0 when discarded

    int hh[5];
    #pragma unroll
    for (int k = 0; k < 5; ++k) {
        int b = ph + k - 2; hh[k] = b < 0 ? 0 : (b > 47 ? 47 : b);
    }

    const int crow = (pcd * 48 + ph) * 48;
    const float2 cv = *(const float2*)(x + crow + w0);
    const v2f ctr   = {cv.x, cv.y};
    const v2f negcK = -K * ctr;         // per-output -c*K, hoisted

    v2f num = {0.f, 0.f};
    v2f den = {0.f, 0.f};

    #pragma unroll 1   // keep body small; j/l fully unrolled
    for (int i = 0; i < 5; ++i) {
        int a = d0 + i - 2; a = a < 0 ? 0 : (a > 47 ? 47 : a);
        const int sbase = (dz + a) * 2304;
        const float Li = (i == 2) ? 0.0f : ((i == 1 || i == 3) ? L1 : L0);
        #pragma unroll
        for (int j = 0; j < 5; ++j) {
            const int rbase = sbase + hh[j] * 48;
            const float2 A = *(const float2*)(x + rbase + a_off);
            const float2 B = *(const float2*)(x + rbase + w0);
            const float2 C = *(const float2*)(x + rbase + c_off);
            // 6-float window [w0-2 .. w0+3], replicate-pad in w
            float win[6];
            win[0] = left  ? B.x : A.x;
            win[1] = left  ? B.x : A.y;
            win[2] = B.x; win[3] = B.y;
            win[4] = right ? B.y : C.x;
            win[5] = right ? B.y : C.y;
            const float Lij = Li + LGc[j];
            #pragma unroll
            for (int l = 0; l < 5; ++l) {
                const float Lc = Lij + LGc[l];
                const v2f p   = {win[l], win[l + 1]};
                const v2f s   = p * K + negcK;          // pk_fma
                const v2f arg = Lc - s * s;             // pk_fma (neg folded)
                const v2f e   = {__builtin_amdgcn_exp2f(arg.x),
                                 __builtin_amdgcn_exp2f(arg.y)};
                num += e * p;                           // pk_fma
                den += e;                               // pk_add
            }
        }
    }

    float2 o2;
    o2.x = num.x / den.x;
    o2.y = num.y / den.y;
    *(float2*)(out + crow + w0) = o2;
}

extern "C" void kernel_launch(void* const* d_in, const int* in_sizes, int n_in,
                              void* d_out, int out_size, void* d_ws, size_t ws_size,
                              hipStream_t stream) {
    const float* x = (const float*)d_in[0];
    float* out = (float*)d_out;
    // 165888 threads (one per w-pair) in 2592 single-wave blocks
    // -> 2.53 waves/SIMD (known-good occupancy from R5)
    hipLaunchKernelGGL(bilateral3d, dim3(2592), dim3(64), 0, stream, x, out);
}

// Round 7
// 63.541 us; speedup vs baseline: 1.0729x; 1.0729x over previous
//
#include <hip/hip_runtime.h>
#include <math.h>

// x: (1,3,48,48,48) fp32, C-contiguous: idx = (cd*48 + h)*48 + w, cd = c*48+d
// out[v] = sum(g*wd*p) / sum(g*wd) -- all normalizations cancel.
// wd*g folded into a single exp2: w = exp2(d^2 * C2 + LG[i]+LG[j]+LG[l])
//   C2   = -1/(2*0.8^2) * log2(e)
//   LG[k]= log2(gauss tap k), sigma=1.1: LG = {L0, L1, 0, L1, L0}
//
// FINAL (reverted to best, R2): six rounds showed the timed graph is
// dominated by the harness's 268 MB d_ws poison fill (~40.5 us @ 83% HBM
// peak, memory-bound) + ~15-20 us fixed graph/restore overhead. Kernel-side
// levers (loads/output 125->18.75, occupancy 1.3->5 waves/SIMD, VALU cuts
// ~2x, packed fp32) all moved the total <= +-3 us ~= fill jitter. This
// simple variant measured best: 64.15 us.

__global__ __launch_bounds__(256)
void bilateral3d(const float* __restrict__ x, float* __restrict__ out) {
    constexpr float C2 = -1.1271055f;
    constexpr float L0 = -2.3846116f;
    constexpr float L1 = -0.5961529f;
    constexpr float LG[5] = {L0, L1, 0.0f, L1, L0};

    const int w0 = blockIdx.x * 16 + threadIdx.x;   // 0..47
    const int h0 = blockIdx.y * 16 + threadIdx.y;   // 0..47
    const int cd = blockIdx.z;                      // c*48 + d
    const int d0 = cd % 48;
    const int dz = cd - d0;                         // c*48

    // hoisted clamped offsets (replicate pad)
    int dd[5], hh[5], ww[5];
    #pragma unroll
    for (int k = 0; k < 5; ++k) {
        int a = d0 + k - 2; dd[k] = a < 0 ? 0 : (a > 47 ? 47 : a);
        int b = h0 + k - 2; hh[k] = b < 0 ? 0 : (b > 47 ? 47 : b);
        int c = w0 + k - 2; ww[k] = c < 0 ? 0 : (c > 47 ? 47 : c);
    }

    // 25 precomputed row bases
    int rb[25];
    #pragma unroll
    for (int i = 0; i < 5; ++i)
        #pragma unroll
        for (int j = 0; j < 5; ++j)
            rb[i * 5 + j] = (dz + dd[i]) * 2304 + hh[j] * 48;

    const int center_idx = (cd * 48 + h0) * 48 + w0;
    const float center = x[center_idx];

    float num = 0.0f, den = 0.0f;

    #pragma unroll
    for (int i = 0; i < 5; ++i) {
        #pragma unroll
        for (int j = 0; j < 5; ++j) {
            const int base = rb[i * 5 + j];
            const float Lij = LG[i] + LG[j];        // compile-time constant
            #pragma unroll
            for (int l = 0; l < 5; ++l) {
                const float p = x[base + ww[l]];
                const float dlt = p - center;
                const float t = dlt * dlt;
                const float e = __builtin_amdgcn_exp2f(fmaf(t, C2, Lij + LG[l]));
                num = fmaf(e, p, num);
                den += e;
            }
        }
    }

    out[center_idx] = num / den;
}

extern "C" void kernel_launch(void* const* d_in, const int* in_sizes, int n_in,
                              void* d_out, int out_size, void* d_ws, size_t ws_size,
                              hipStream_t stream) {
    const float* x = (const float*)d_in[0];
    float* out = (float*)d_out;

    dim3 block(16, 16, 1);
    dim3 grid(3, 3, 3 * 48);   // w-tiles, h-tiles, c*d slices
    hipLaunchKernelGGL(bilateral3d, grid, block, 0, stream, x, out);
}